// Round 5
// baseline (741.684 us; speedup 1.0000x reference)
//
#include <hip/hip_runtime.h>
#include <math.h>

#define LRELU_A 0.2f
#define NEGBIG (-9.0e15f)

typedef _Float16 f16;
typedef _Float16 f16x8 __attribute__((ext_vector_type(8)));
typedef _Float16 f16x4 __attribute__((ext_vector_type(4)));
typedef float floatx4 __attribute__((ext_vector_type(4)));

__device__ __forceinline__ float rcpf(float x){ return __builtin_amdgcn_rcpf(x); }
__device__ __forceinline__ float sigm_f(float x){ return rcpf(1.0f + __expf(-x)); }
__device__ __forceinline__ float tanh_f(float x){ return 1.0f - 2.0f*rcpf(1.0f + __expf(2.0f*x)); }
__device__ __forceinline__ float sigm(float x){ return rcpf(1.0f+__expf(-x)); }
__device__ __forceinline__ f16x8 load_cvt8(const float* __restrict__ p){
    float4 a = *(const float4*)p; float4 b = *(const float4*)(p+4);
    f16x8 r; r[0]=(f16)a.x; r[1]=(f16)a.y; r[2]=(f16)a.z; r[3]=(f16)a.w;
    r[4]=(f16)b.x; r[5]=(f16)b.y; r[6]=(f16)b.z; r[7]=(f16)b.w;
    return r;
}
#define MFMA16(A,B,C) __builtin_amdgcn_mfma_f32_16x16x32_f16((A),(B),(C),0,0,0)

// ---------------------------------------------------------------------------
// One prep kernel: Wcat1 | WcatA | WT | fwT | sector bucketing.
// Wcat layout: rows 0..255 [Wih_rz|Whh_rz]; 256..383 [Wih_n|0]; 384..511 [0|Whh_n]
// ---------------------------------------------------------------------------
__global__ __launch_bounds__(256) void prep_kernel(
    const float* __restrict__ g1Wih, const float* __restrict__ g1Whh,
    const float* __restrict__ gaWih, const float* __restrict__ gaWhh,
    const float* __restrict__ giW,   const float* __restrict__ fw,
    const int* __restrict__ sec,
    f16* __restrict__ Wcat1, f16* __restrict__ WcatA,
    f16* __restrict__ WT, f16* __restrict__ fwT,
    int* __restrict__ memflat, int* __restrict__ cnt, int* __restrict__ base)
{
    __shared__ int cs[16], wsc[16];
    const int b = blockIdx.x, tid = threadIdx.x;
    if (b < 160){                      // Wcat1: INF=16, INFPAD=32, KTOT=160
        for (int idx = b*256+tid; idx < 512*160; idx += 160*256){
            int r = idx/160, k = idx - r*160;
            float v = 0.0f;
            if (r < 256){ if (k < 32){ if (k < 16) v = g1Wih[r*16+k]; } else v = g1Whh[r*128 + (k-32)]; }
            else if (r < 384){ if (k < 16) v = g1Wih[r*16+k]; }
            else { if (k >= 32) v = g1Whh[(r-128)*128 + (k-32)]; }
            Wcat1[idx] = (f16)v;
        }
    } else if (b < 416){               // WcatA: INF=128, INFPAD=128, KTOT=256
        for (int idx = (b-160)*256+tid; idx < 512*256; idx += 256*256){
            int r = idx >> 8, k = idx & 255;
            float v = 0.0f;
            if (r < 256){ v = (k < 128) ? gaWih[r*128+k] : gaWhh[r*128 + (k-128)]; }
            else if (r < 384){ if (k < 128) v = gaWih[r*128+k]; }
            else { if (k >= 128) v = gaWhh[(r-128)*128 + (k-128)]; }
            WcatA[idx] = (f16)v;
        }
    } else if (b < 480){               // WT = giW^T (128x128)
        int idx = (b-416)*256+tid;
        int r = idx >> 7, c = idx & 127;
        WT[c*128 + r] = (f16)giW[idx];
    } else if (b < 672){               // fwT = fw^T (384x128 -> 128x384)
        int idx = (b-480)*256+tid;
        int r = idx >> 7, c = idx & 127;
        fwT[c*384 + r] = (f16)fw[idx];
    } else {                           // bucket
        if (tid < 16) cs[tid] = 0;
        __syncthreads();
        for (int s = tid; s < 2048; s += 256) atomicAdd(&cs[sec[s]], 1);
        __syncthreads();
        if (tid == 0){
            int acc = 0;
            for (int g=0; g<16; g++){ cnt[g]=cs[g]; base[g]=acc; wsc[g]=acc; acc+=cs[g]; }
        }
        __syncthreads();
        for (int s = tid; s < 2048; s += 256){
            int g = sec[s];
            int p = atomicAdd(&wsc[g], 1);
            memflat[p] = s;
        }
    }
}

// ---------------------------------------------------------------------------
// Short GRU+attn. M=32 seqs/block, 8 waves, T=5. Gate-partitioned MFMA,
// lagged unnormalized softmax (no max, no rescale), 1 barrier/step.
// ---------------------------------------------------------------------------
__global__ __launch_bounds__(512,4) void gru_short(
    const float* __restrict__ x, const f16* __restrict__ Wcat,
    const float* __restrict__ bih, const float* __restrict__ bhh,
    const float* __restrict__ aw, const float* __restrict__ ab,
    f16* __restrict__ out)
{
    __shared__ __align__(16) f16 xs[5][32][40];
    __shared__ __align__(16) f16 hs[2][32][136];
    __shared__ float scpart[2][8][32];
    const int tid = threadIdx.x, w = tid>>6, lane = tid&63;
    const int c = lane&15, quad = lane>>4;
    const int s0 = blockIdx.x*32;

    { f16x4 z4 = {0,0,0,0};
      f16x4* zx = (f16x4*)&xs[0][0][0];
      for (int i=tid; i<1600; i+=512) zx[i] = z4;
      f16x4* zh = (f16x4*)&hs[1][0][0];
      for (int i=tid; i<1088; i+=512) zh[i] = z4; }
    for (int i=tid; i<640; i+=512){
        int s = i/20, q = i - 20*s;
        float4 v = *(const float4*)&x[(size_t)(s0+s)*80 + q*4];
        int t = (q*4)>>4, f = (q*4)&15;
        f16x4 h4; h4[0]=(f16)v.x; h4[1]=(f16)v.y; h4[2]=(f16)v.z; h4[3]=(f16)v.w;
        *(f16x4*)&xs[t][s][f] = h4;
    }
    const int jrow = w*16 + c;
    f16x8 Ar[5], Az[5], Agi, Agh[4];
#pragma unroll
    for (int kb=0;kb<5;kb++){
        Ar[kb] = *(const f16x8*)&Wcat[(size_t)(jrow)*160 + kb*32 + quad*8];
        Az[kb] = *(const f16x8*)&Wcat[(size_t)(128+jrow)*160 + kb*32 + quad*8];
    }
    Agi = *(const f16x8*)&Wcat[(size_t)(256+jrow)*160 + quad*8];
#pragma unroll
    for (int i=0;i<4;i++)
        Agh[i] = *(const f16x8*)&Wcat[(size_t)(384+jrow)*160 + 32 + i*32 + quad*8];

    float brz_r[4], brz_z[4], b_in[4], b_hn[4], awr[4];
#pragma unroll
    for (int r=0;r<4;r++){
        int j = w*16 + quad*4 + r;
        brz_r[r] = bih[j] + bhh[j];
        brz_z[r] = bih[128+j] + bhh[128+j];
        b_in[r] = bih[256+j]; b_hn[r] = bhh[256+j];
        awr[r] = aw[j];
    }
    const float abv = ab[0];
    float hreg[2][4], aacc[2][4], l_[2] = {0.0f, 0.0f};
#pragma unroll
    for (int st=0; st<2; st++)
#pragma unroll
        for (int r=0;r<4;r++){ hreg[st][r]=0.0f; aacc[st][r]=0.0f; }
    __syncthreads();

#pragma unroll 1
    for (int t=0; t<5; ++t){
        const int rp = (t&1)^1, wp = t&1;
        f16x8 Bx[2], Bh[2][4];
#pragma unroll
        for (int st=0; st<2; st++){
            Bx[st] = *(const f16x8*)&xs[t][st*16+c][quad*8];
#pragma unroll
            for (int i=0;i<4;i++)
                Bh[st][i] = *(const f16x8*)&hs[rp][st*16+c][i*32+quad*8];
        }
        // lagged attention: apply step t-1's weight to h_{t-1} (still in hreg)
        if (t > 0){
#pragma unroll
            for (int st=0; st<2; st++){
                float sc = abv;
#pragma unroll
                for (int ww=0; ww<8; ww++) sc += scpart[rp][ww][st*16+c];
                float e = __expf(sc);
                l_[st] += e;
#pragma unroll
                for (int r=0;r<4;r++) aacc[st][r] += e*hreg[st][r];
            }
        }
        float sp[2];
#pragma unroll
        for (int st=0; st<2; st++){
            floatx4 ar = {0,0,0,0}, az = {0,0,0,0}, agi = {0,0,0,0}, agh = {0,0,0,0};
            ar = MFMA16(Ar[0], Bx[st], ar);
            az = MFMA16(Az[0], Bx[st], az);
            agi = MFMA16(Agi, Bx[st], agi);
#pragma unroll
            for (int i=0;i<4;i++){
                ar = MFMA16(Ar[1+i], Bh[st][i], ar);
                az = MFMA16(Az[1+i], Bh[st][i], az);
                agh = MFMA16(Agh[i], Bh[st][i], agh);
            }
            f16x4 h4;
            sp[st] = 0.0f;
#pragma unroll
            for (int r=0;r<4;r++){
                float rg = sigm_f(ar[r] + brz_r[r]);
                float zg = sigm_f(az[r] + brz_z[r]);
                float ng = tanh_f(agi[r] + b_in[r] + rg*(agh[r] + b_hn[r]));
                float hn = fmaf(zg, hreg[st][r] - ng, ng);
                hreg[st][r] = hn; h4[r] = (f16)hn;
                sp[st] += hn * awr[r];
            }
            *(f16x4*)&hs[wp][st*16 + c][w*16 + quad*4] = h4;
        }
#pragma unroll
        for (int st=0; st<2; st++){
            sp[st] += __shfl_xor(sp[st], 16);
            sp[st] += __shfl_xor(sp[st], 32);
        }
        if (lane < 16){ scpart[wp][w][lane] = sp[0]; scpart[wp][w][16+lane] = sp[1]; }
        __syncthreads();
    }
    // drain last step (t=4 wrote scpart[0], hreg holds h_4)
#pragma unroll
    for (int st=0; st<2; st++){
        float sc = abv;
#pragma unroll
        for (int ww=0; ww<8; ww++) sc += scpart[0][ww][st*16+c];
        float e = __expf(sc);
        l_[st] += e;
        float inv = rcpf(l_[st]);
        f16x4 h4;
#pragma unroll
        for (int r=0;r<4;r++) h4[r] = (f16)((aacc[st][r] + e*hreg[st][r])*inv);
        *(f16x4*)&hs[0][st*16 + c][w*16 + quad*4] = h4;
    }
    __syncthreads();
    { int s = tid>>4, p = tid&15;
      *(f16x8*)&out[(size_t)(s0+s)*128 + p*8] = *(const f16x8*)&hs[0][s][p*8]; }
}

// ---------------------------------------------------------------------------
// la GRU+attn. M=8 real seqs/block (16-tile padded), 256 blocks, T=32.
// Same lagged-softmax structure, 1 barrier/step.
// ---------------------------------------------------------------------------
__global__ __launch_bounds__(512,4) void gru_la(
    const f16* __restrict__ xseq, const f16* __restrict__ Wcat,
    const float* __restrict__ bih, const float* __restrict__ bhh,
    const float* __restrict__ aw, const float* __restrict__ ab,
    f16* __restrict__ out)
{
    __shared__ __align__(16) f16 xs[2][16][136];
    __shared__ __align__(16) f16 hs[2][16][136];
    __shared__ float scpart[2][8][16];
    const int tid = threadIdx.x, w = tid>>6, lane = tid&63;
    const int c = lane&15, quad = lane>>4;
    const int s0 = blockIdx.x*8;

    { f16x4 z4 = {0,0,0,0};
      f16x4* za = (f16x4*)&xs[0][0][0];
      for (int i=tid; i<1088; i+=512) za[i] = z4;
      f16x4* zh = (f16x4*)&hs[0][0][0];
      for (int i=tid; i<1088; i+=512) zh[i] = z4; }
    __syncthreads();
    if (tid < 128){
        int s = tid>>4, p = tid&15;
        *(f16x8*)&xs[0][s][p*8] = *(const f16x8*)&xseq[((size_t)(s0+s)*32 + 0)*128 + p*8];
    }
    const int jrow = w*16 + c;
    f16x8 Ar[8], Az[8], Agi[4], Agh[4];
#pragma unroll
    for (int kb=0;kb<8;kb++){
        Ar[kb] = *(const f16x8*)&Wcat[(size_t)(jrow)*256 + kb*32 + quad*8];
        Az[kb] = *(const f16x8*)&Wcat[(size_t)(128+jrow)*256 + kb*32 + quad*8];
    }
#pragma unroll
    for (int i=0;i<4;i++){
        Agi[i] = *(const f16x8*)&Wcat[(size_t)(256+jrow)*256 + i*32 + quad*8];
        Agh[i] = *(const f16x8*)&Wcat[(size_t)(384+jrow)*256 + 128 + i*32 + quad*8];
    }
    float brz_r[4], brz_z[4], b_in[4], b_hn[4], awr[4];
#pragma unroll
    for (int r=0;r<4;r++){
        int j = w*16 + quad*4 + r;
        brz_r[r] = bih[j] + bhh[j];
        brz_z[r] = bih[128+j] + bhh[128+j];
        b_in[r] = bih[256+j]; b_hn[r] = bhh[256+j];
        awr[r] = aw[j];
    }
    const float abv = ab[0];
    float hreg[4] = {0,0,0,0}, aacc[4] = {0,0,0,0}, l_ = 0.0f;
    __syncthreads();

#pragma unroll 1
    for (int t=0; t<32; ++t){
        const int rp = (t&1)^1, wp = t&1, xp = t&1;
        f16x8 Bx[4], Bh[4];
#pragma unroll
        for (int i=0;i<4;i++){
            Bx[i] = *(const f16x8*)&xs[xp][c][i*32+quad*8];
            Bh[i] = *(const f16x8*)&hs[rp][c][i*32+quad*8];
        }
        f16x8 xstage;
        const bool do_stage = (t < 31) && (tid < 128);
        if (do_stage){
            int s = tid>>4, p = tid&15;
            xstage = *(const f16x8*)&xseq[((size_t)(s0+s)*32 + t+1)*128 + p*8];
        }
        if (t > 0){
            float sc = abv;
#pragma unroll
            for (int ww=0; ww<8; ww++) sc += scpart[rp][ww][c];
            float e = __expf(sc);
            l_ += e;
#pragma unroll
            for (int r=0;r<4;r++) aacc[r] += e*hreg[r];
        }
        floatx4 ar = {0,0,0,0}, az = {0,0,0,0}, agi = {0,0,0,0}, agh = {0,0,0,0};
#pragma unroll
        for (int i=0;i<4;i++){
            ar = MFMA16(Ar[i], Bx[i], ar);
            az = MFMA16(Az[i], Bx[i], az);
            agi = MFMA16(Agi[i], Bx[i], agi);
        }
#pragma unroll
        for (int i=0;i<4;i++){
            ar = MFMA16(Ar[4+i], Bh[i], ar);
            az = MFMA16(Az[4+i], Bh[i], az);
            agh = MFMA16(Agh[i], Bh[i], agh);
        }
        f16x4 h4;
        float sp = 0.0f;
#pragma unroll
        for (int r=0;r<4;r++){
            float rg = sigm_f(ar[r] + brz_r[r]);
            float zg = sigm_f(az[r] + brz_z[r]);
            float ng = tanh_f(agi[r] + b_in[r] + rg*(agh[r] + b_hn[r]));
            float hn = fmaf(zg, hreg[r] - ng, ng);
            hreg[r] = hn; h4[r] = (f16)hn;
            sp += hn * awr[r];
        }
        *(f16x4*)&hs[wp][c][w*16 + quad*4] = h4;
        if (do_stage){
            int s = tid>>4, p = tid&15;
            *(f16x8*)&xs[xp^1][s][p*8] = xstage;
        }
        sp += __shfl_xor(sp, 16);
        sp += __shfl_xor(sp, 32);
        if (lane < 16) scpart[wp][w][lane] = sp;
        __syncthreads();
    }
    // drain (t=31 wrote scpart[1])
    {
        float sc = abv;
#pragma unroll
        for (int ww=0; ww<8; ww++) sc += scpart[1][ww][c];
        float e = __expf(sc);
        l_ += e;
        float inv = rcpf(l_);
        f16x4 h4;
#pragma unroll
        for (int r=0;r<4;r++) h4[r] = (f16)((aacc[r] + e*hreg[r])*inv);
        *(f16x4*)&hs[1][c][w*16 + quad*4] = h4;
    }
    __syncthreads();
    if (tid < 128){
        int s = tid>>4, p = tid&15;
        *(f16x8*)&out[(size_t)(s0+s)*128 + p*8] = *(const f16x8*)&hs[1][s][p*8];
    }
}

// ---------------------------------------------------------------------------
// gat_prep: per 32 sorted rows — Wh=h@W (MFMA), sorted f16 Whs, ers, el[orig]
// ---------------------------------------------------------------------------
__global__ __launch_bounds__(256) void gat_prep(
    const f16* __restrict__ shrt16, const f16* __restrict__ WT,
    const float* __restrict__ gia, const int* __restrict__ memflat,
    f16* __restrict__ Whs, float* __restrict__ ers, float* __restrict__ el)
{
    __shared__ __align__(16) float tbuf[32][132];
    __shared__ int rows[32];
    const int tid = threadIdx.x, w = tid>>6, lane = tid&63;
    const int c = lane&15, quad = lane>>4;
    const int p0 = blockIdx.x*32;
    if (tid < 32) rows[tid] = memflat[p0 + tid];
    __syncthreads();
    f16x8 A[2][4];
#pragma unroll
    for (int mt=0;mt<2;mt++)
#pragma unroll
        for (int kb=0;kb<4;kb++)
            A[mt][kb] = *(const f16x8*)&shrt16[((size_t)rows[mt*16+c]*32 + 31)*128 + kb*32 + quad*8];
#pragma unroll
    for (int i=0;i<2;i++){
        int jb = w*2 + i;
        f16x8 B[4];
#pragma unroll
        for (int kb=0;kb<4;kb++)
            B[kb] = *(const f16x8*)&WT[(size_t)(jb*16+c)*128 + kb*32 + quad*8];
        floatx4 acc[2] = {{0,0,0,0},{0,0,0,0}};
#pragma unroll
        for (int kb=0;kb<4;kb++){
            acc[0] = MFMA16(A[0][kb], B[kb], acc[0]);
            acc[1] = MFMA16(A[1][kb], B[kb], acc[1]);
        }
#pragma unroll
        for (int mt=0;mt<2;mt++)
#pragma unroll
            for (int r=0;r<4;r++)
                tbuf[mt*16 + quad*4 + r][jb*16 + c] = acc[mt][r];
    }
    __syncthreads();
    // sorted f16 Wh
    for (int i=tid; i<1024; i+=256){
        int s = i>>5, p = i&31;
        float4 v = *(const float4*)&tbuf[s][p*4];
        f16x4 h4; h4[0]=(f16)v.x; h4[1]=(f16)v.y; h4[2]=(f16)v.z; h4[3]=(f16)v.w;
        *(f16x4*)&Whs[(size_t)(p0+s)*128 + p*4] = h4;
    }
    // el (orig-indexed), er (sorted)
    for (int k=0; k<8; k++){
        int row = w*8 + k;
        float w0 = tbuf[row][lane], w1 = tbuf[row][64+lane];
        float v1 = w0*gia[lane]     + w1*gia[64+lane];
        float v2 = w0*gia[128+lane] + w1*gia[192+lane];
#pragma unroll
        for (int off=32; off; off>>=1){ v1 += __shfl_down(v1,off); v2 += __shfl_down(v2,off); }
        if (lane==0){ el[rows[row]] = v1; ers[p0+row] = v2; }
    }
}

// ---------------------------------------------------------------------------
// GAT intra, member-list. One wave per row; streams sorted f16 Wh.
// ---------------------------------------------------------------------------
__global__ __launch_bounds__(256) void gat_intra_mem_kernel(
    const f16* __restrict__ Whs, const float* __restrict__ ers,
    const float* __restrict__ el, const int* __restrict__ sec,
    const int* __restrict__ cnt, const int* __restrict__ base,
    f16* __restrict__ outp, int S)
{
    int wave = threadIdx.x>>6, lane = threadIdx.x&63;
    int i = blockIdx.x*4 + wave;
    if (i>=S) return;
    int g = sec[i];
    int n = cnt[g], b = base[g];
    float eli = el[i];
    float m = -INFINITY;
    for (int jj=lane; jj<n; jj+=64){
        float v = eli + ers[b+jj]; v = v>0.f? v : LRELU_A*v;
        m = fmaxf(m, v);
    }
#pragma unroll
    for (int off=32; off; off>>=1) m = fmaxf(m, __shfl_xor(m, off));
    float l = 0.f, c0=0.f, c1=0.f;
#pragma unroll 4
    for (int jj=0; jj<n; jj++){
        float v = eli + ers[b+jj]; v = v>0.f? v : LRELU_A*v;
        float p = __expf(v-m);
        l += p;
        c0 += p*(float)Whs[(size_t)(b+jj)*128 + lane];
        c1 += p*(float)Whs[(size_t)(b+jj)*128 + 64 + lane];
    }
    float il = rcpf(l);
    c0 *= il; c1 *= il;
    outp[(size_t)i*128+lane]    = (f16)(c0>0.f? c0 : expm1f(c0));
    outp[(size_t)i*128+64+lane] = (f16)(c1>0.f? c1 : expm1f(c1));
}

// ---------------------------------------------------------------------------
// lg: T=1 GRU simplification via MFMA
// ---------------------------------------------------------------------------
__global__ __launch_bounds__(256) void lg_mfma(
    const f16* __restrict__ intra16, const float* __restrict__ Wih,
    const float* __restrict__ bih, const float* __restrict__ bhh,
    f16* __restrict__ lgout)
{
    __shared__ __align__(16) f16 tbuf[32][136];
    const int tid = threadIdx.x, w = tid>>6, lane = tid&63;
    const int c = lane&15, quad = lane>>4;
    const int s0 = blockIdx.x*32;
    f16x8 A[2][4];
#pragma unroll
    for (int mt=0;mt<2;mt++)
#pragma unroll
        for (int kb=0;kb<4;kb++)
            A[mt][kb] = *(const f16x8*)&intra16[(size_t)(s0+mt*16+c)*128 + kb*32 + quad*8];
#pragma unroll
    for (int i=0;i<2;i++){
        int jb = w*2 + i;
        int j = jb*16 + c;
        f16x8 Br[4], Bz[4], Bn[4];
#pragma unroll
        for (int kb=0;kb<4;kb++){
            Br[kb] = load_cvt8(&Wih[(size_t)(j)*128 + kb*32 + quad*8]);
            Bz[kb] = load_cvt8(&Wih[(size_t)(128+j)*128 + kb*32 + quad*8]);
            Bn[kb] = load_cvt8(&Wih[(size_t)(256+j)*128 + kb*32 + quad*8]);
        }
        float b_r = bih[j] + bhh[j];
        float b_z = bih[128+j] + bhh[128+j];
        float b_i = bih[256+j], b_h = bhh[256+j];
        floatx4 ar[2] = {{0,0,0,0},{0,0,0,0}};
        floatx4 az[2] = {{0,0,0,0},{0,0,0,0}};
        floatx4 an[2] = {{0,0,0,0},{0,0,0,0}};
#pragma unroll
        for (int kb=0;kb<4;kb++)
#pragma unroll
            for (int mt=0;mt<2;mt++){
                ar[mt] = MFMA16(A[mt][kb], Br[kb], ar[mt]);
                az[mt] = MFMA16(A[mt][kb], Bz[kb], az[mt]);
                an[mt] = MFMA16(A[mt][kb], Bn[kb], an[mt]);
            }
#pragma unroll
        for (int mt=0;mt<2;mt++)
#pragma unroll
            for (int r=0;r<4;r++){
                float rg = sigm_f(ar[mt][r] + b_r);
                float zg = sigm_f(az[mt][r] + b_z);
                float ng = tanh_f(an[mt][r] + b_i + rg*b_h);
                tbuf[mt*16 + quad*4 + r][j] = (f16)((1.0f - zg)*ng);
            }
    }
    __syncthreads();
    for (int i=tid; i<512; i+=256){
        int s = i>>4, p = i&15;
        *(f16x8*)&lgout[(size_t)(s0+s)*128 + p*8] = *(const f16x8*)&tbuf[s][p*8];
    }
}

// sector means via flat member lists
__global__ __launch_bounds__(128) void sector_mean_mem_kernel(
    const f16* __restrict__ lg, const int* __restrict__ memflat,
    const int* __restrict__ cnt, const int* __restrict__ base,
    float* __restrict__ secf)
{
    int g = blockIdx.x, j = threadIdx.x;
    int n = cnt[g];
    const int* ml = memflat + base[g];
    float sum=0.f;
    for (int k=0;k<n;k++) sum += (float)lg[(size_t)ml[k]*128 + j];
    secf[g*128+j] = sum * rcpf(fmaxf((float)n,1.0f));
}

__global__ __launch_bounds__(256) void gat_inter_kernel(
    const float* __restrict__ secf, const int* __restrict__ adj,
    const float* __restrict__ W, const float* __restrict__ a,
    float* __restrict__ outp)
{
    __shared__ __align__(16) float hs[16][132];
    __shared__ __align__(16) float Whs[16][132];
    __shared__ float el[16], er[16];
    __shared__ float att[16][16];
    const int tid=threadIdx.x;
    for (int idx=tid; idx<2048; idx+=256){ int s=idx>>7,j=idx&127; hs[s][j]=secf[idx]; }
    __syncthreads();
#pragma unroll 1
    for (int i=0;i<8;i++){
        int idx=i*256+tid; int o=idx&127, s=idx>>7;
        float a0=0.f,a1=0.f,a2=0.f,a3=0.f;
        for (int j=0;j<128;j+=4){
            a0 += hs[s][j]  *W[(j  )*128+o];
            a1 += hs[s][j+1]*W[(j+1)*128+o];
            a2 += hs[s][j+2]*W[(j+2)*128+o];
            a3 += hs[s][j+3]*W[(j+3)*128+o];
        }
        Whs[s][o]=(a0+a1)+(a2+a3);
    }
    __syncthreads();
    if (tid<32){
        int s=tid&15; int second = tid>>4;
        const float* av = a + (second?128:0);
        float acc=0.f; for(int o=0;o<128;o++) acc += Whs[s][o]*av[o];
        if (second) er[s]=acc; else el[s]=acc;
    }
    __syncthreads();
    if (tid<16){
        int i=tid; float m=NEGBIG; float e[16];
        for(int j=0;j<16;j++){
            float v = el[i]+er[j]; v = v>0.f? v : LRELU_A*v;
            e[j] = (adj[i*16+j]>0)? v : NEGBIG;
            m = fmaxf(m,e[j]);
        }
        float l=0.f;
        for(int j=0;j<16;j++){ float p=__expf(e[j]-m); att[i][j]=p; l+=p; }
        float il = rcpf(l);
        for(int j=0;j<16;j++) att[i][j] *= il;
    }
    __syncthreads();
#pragma unroll
    for (int i=0;i<8;i++){
        int idx=i*256+tid; int o=idx&127, s=idx>>7;
        float acc=0.f;
#pragma unroll
        for(int j=0;j<16;j++) acc += att[s][j]*Whs[j][o];
        outp[s*128+o] = acc>0.f? acc : expm1f(acc);
    }
}

// ---------------------------------------------------------------------------
// fused = [lg|la|sec_ps] @ fw + fb, then both heads in-kernel
// ---------------------------------------------------------------------------
__global__ __launch_bounds__(256) void fused_mfma(
    const f16* __restrict__ lg16, const f16* __restrict__ la16,
    const float* __restrict__ seco, const int* __restrict__ sec,
    const f16* __restrict__ fwT,
    const float* __restrict__ fb, const float* __restrict__ rw,
    const float* __restrict__ rb, const float* __restrict__ mw,
    const float* __restrict__ mb, float* __restrict__ outp)
{
    __shared__ float rpart[4][32], mpart[4][32];
    const int tid = threadIdx.x, w = tid>>6, lane = tid&63;
    const int c = lane&15, quad = lane>>4;
    const int s0 = blockIdx.x*32;
    f16x8 A[2][12];
#pragma unroll
    for (int mt=0;mt<2;mt++){
        int row = s0 + mt*16 + c;
        int g = sec[row];
#pragma unroll
        for (int kb=0;kb<4;kb++){
            A[mt][kb]   = *(const f16x8*)&lg16[(size_t)row*128 + kb*32 + quad*8];
            A[mt][4+kb] = *(const f16x8*)&la16[(size_t)row*128 + kb*32 + quad*8];
            A[mt][8+kb] = load_cvt8(&seco[(size_t)g*128 + kb*32 + quad*8]);
        }
    }
    float rsum[2][4] = {{0,0,0,0},{0,0,0,0}};
    float msum[2][4] = {{0,0,0,0},{0,0,0,0}};
#pragma unroll
    for (int i=0;i<2;i++){
        int jb = w*2 + i;
        int col = jb*16 + c;
        f16x8 B[12];
#pragma unroll
        for (int kb=0;kb<12;kb++)
            B[kb] = *(const f16x8*)&fwT[(size_t)col*384 + kb*32 + quad*8];
        floatx4 acc[2] = {{0,0,0,0},{0,0,0,0}};
#pragma unroll
        for (int kb=0;kb<12;kb++){
            acc[0] = MFMA16(A[0][kb], B[kb], acc[0]);
            acc[1] = MFMA16(A[1][kb], B[kb], acc[1]);
        }
        float fbv = fb[col], rwv = rw[col], mwv = mw[col];
#pragma unroll
        for (int mt=0;mt<2;mt++)
#pragma unroll
            for (int r=0;r<4;r++){
                float fu = acc[mt][r] + fbv;
                rsum[mt][r] += fu*rwv;
                msum[mt][r] += fu*mwv;
            }
    }
#pragma unroll
    for (int mt=0;mt<2;mt++)
#pragma unroll
        for (int r=0;r<4;r++){
#pragma unroll
            for (int off=1; off<16; off<<=1){
                rsum[mt][r] += __shfl_xor(rsum[mt][r], off);
                msum[mt][r] += __shfl_xor(msum[mt][r], off);
            }
            if (c==0){
                rpart[w][mt*16 + quad*4 + r] = rsum[mt][r];
                mpart[w][mt*16 + quad*4 + r] = msum[mt][r];
            }
        }
    __syncthreads();
    if (tid < 32){
        int s = tid;
        float rs = rb[0], ms = mb[0];
#pragma unroll
        for (int ww=0; ww<4; ww++){ rs += rpart[ww][s]; ms += mpart[ww][s]; }
        outp[s0+s] = rs;
        outp[2048 + s0 + s] = sigm(ms);
    }
}

extern "C" void kernel_launch(void* const* d_in, const int* in_sizes, int n_in,
                              void* d_out, int out_size, void* d_ws, size_t ws_size,
                              hipStream_t stream) {
    const float* sf    = (const float*)d_in[0];
    const int*   sec   = (const int*)  d_in[1];
    const int*   adj   = (const int*)  d_in[2];
    const float* g1Wih = (const float*)d_in[3];
    const float* g1Whh = (const float*)d_in[4];
    const float* g1bih = (const float*)d_in[5];
    const float* g1bhh = (const float*)d_in[6];
    const float* a1w   = (const float*)d_in[7];
    const float* a1b   = (const float*)d_in[8];
    const float* giW   = (const float*)d_in[9];
    const float* gia   = (const float*)d_in[10];
    const float* ggWih = (const float*)d_in[11];
    const float* ggbih = (const float*)d_in[13];
    const float* ggbhh = (const float*)d_in[14];
    const float* gaWih = (const float*)d_in[17];
    const float* gaWhh = (const float*)d_in[18];
    const float* gabih = (const float*)d_in[19];
    const float* gabhh = (const float*)d_in[20];
    const float* aaw   = (const float*)d_in[21];
    const float* aab   = (const float*)d_in[22];
    const float* geW   = (const float*)d_in[23];
    const float* gea   = (const float*)d_in[24];
    const float* fw    = (const float*)d_in[25];
    const float* fb    = (const float*)d_in[26];
    const float* rw    = (const float*)d_in[27];
    const float* rb    = (const float*)d_in[28];
    const float* mw    = (const float*)d_in[29];
    const float* mb    = (const float*)d_in[30];

    char* p = (char*)d_ws;
    f16*   shrt16 = (f16*)p;   p += (size_t)65536*128*2;
    f16*   intra16= (f16*)p;   p += (size_t)262144*2;
    f16*   lg16   = (f16*)p;   p += (size_t)262144*2;
    f16*   la16   = (f16*)p;   p += (size_t)262144*2;
    f16*   Whs    = (f16*)p;   p += (size_t)262144*2;
    f16*   Wcat1  = (f16*)p;   p += (size_t)512*160*2;
    f16*   WcatA  = (f16*)p;   p += (size_t)512*256*2;
    f16*   WT     = (f16*)p;   p += (size_t)16384*2;
    f16*   fwT    = (f16*)p;   p += (size_t)49152*2;
    float* el     = (float*)p; p += 2048*4;
    float* ers    = (float*)p; p += 2048*4;
    float* secf   = (float*)p; p += 2048*4;
    float* seco   = (float*)p; p += 2048*4;
    int*   memflat= (int*)p;   p += 2048*4;
    int*   cnt    = (int*)p;   p += 16*4;
    int*   basep  = (int*)p;   p += 16*4;

    // 0. all weight prep + bucketing in one launch
    prep_kernel<<<673,256,0,stream>>>(g1Wih, g1Whh, gaWih, gaWhh, giW, fw, sec,
                                      Wcat1, WcatA, WT, fwT, memflat, cnt, basep);
    // 1. short GRU+attn (65536 windows, T=5)
    gru_short<<<2048,512,0,stream>>>(sf, Wcat1, g1bih, g1bhh, a1w, a1b, shrt16);
    // 2. intra-sector GAT (prep fused: Wh + el/er + sorted gather)
    gat_prep<<<64,256,0,stream>>>(shrt16, WT, gia, memflat, Whs, ers, el);
    gat_intra_mem_kernel<<<512,256,0,stream>>>(Whs, ers, el, sec, cnt, basep, intra16, 2048);
    // 3. lg (T=1 simplification)
    lg_mfma<<<64,256,0,stream>>>(intra16, ggWih, ggbih, ggbhh, lg16);
    // 4. la GRU+attn (2048 seqs, T=32, M=8 -> all CUs)
    gru_la<<<256,512,0,stream>>>(shrt16, WcatA, gabih, gabhh, aaw, aab, la16);
    // 5. sector means
    sector_mean_mem_kernel<<<16,128,0,stream>>>(lg16, memflat, cnt, basep, secf);
    // 6. inter-sector GAT
    gat_inter_kernel<<<1,256,0,stream>>>(secf, adj, geW, gea, seco);
    // 7. fusion + heads
    fused_mfma<<<64,256,0,stream>>>(lg16, la16, seco, sec, fwT, fb, rw, rb, mw, mb, (float*)d_out);
}

// Round 6
// 356.203 us; speedup vs baseline: 2.0822x; 2.0822x over previous
//
#include <hip/hip_runtime.h>
#include <math.h>

#define LRELU_A 0.2f
#define NEGBIG (-9.0e15f)

typedef _Float16 f16;
typedef _Float16 f16x8 __attribute__((ext_vector_type(8)));
typedef _Float16 f16x4 __attribute__((ext_vector_type(4)));
typedef float floatx4 __attribute__((ext_vector_type(4)));

__device__ __forceinline__ float rcpf(float x){ return __builtin_amdgcn_rcpf(x); }
__device__ __forceinline__ float sigm_f(float x){ return rcpf(1.0f + __expf(-x)); }
__device__ __forceinline__ float tanh_f(float x){ return 1.0f - 2.0f*rcpf(1.0f + __expf(2.0f*x)); }
__device__ __forceinline__ float sigm(float x){ return rcpf(1.0f+__expf(-x)); }
__device__ __forceinline__ f16x8 load_cvt8(const float* __restrict__ p){
    float4 a = *(const float4*)p; float4 b = *(const float4*)(p+4);
    f16x8 r; r[0]=(f16)a.x; r[1]=(f16)a.y; r[2]=(f16)a.z; r[3]=(f16)a.w;
    r[4]=(f16)b.x; r[5]=(f16)b.y; r[6]=(f16)b.z; r[7]=(f16)b.w;
    return r;
}
#define MFMA16(A,B,C) __builtin_amdgcn_mfma_f32_16x16x32_f16((A),(B),(C),0,0,0)

// ---------------------------------------------------------------------------
// One prep kernel: Wcat1 | WcatA | WT | fwT | sector bucketing.
// Wcat layout: rows 0..255 [Wih_rz|Whh_rz]; 256..383 [Wih_n|0]; 384..511 [0|Whh_n]
// ---------------------------------------------------------------------------
__global__ __launch_bounds__(256) void prep_kernel(
    const float* __restrict__ g1Wih, const float* __restrict__ g1Whh,
    const float* __restrict__ gaWih, const float* __restrict__ gaWhh,
    const float* __restrict__ giW,   const float* __restrict__ fw,
    const int* __restrict__ sec,
    f16* __restrict__ Wcat1, f16* __restrict__ WcatA,
    f16* __restrict__ WT, f16* __restrict__ fwT,
    int* __restrict__ memflat, int* __restrict__ cnt, int* __restrict__ base)
{
    __shared__ int cs[16], wsc[16];
    const int b = blockIdx.x, tid = threadIdx.x;
    if (b < 160){                      // Wcat1: INF=16, INFPAD=32, KTOT=160
        for (int idx = b*256+tid; idx < 512*160; idx += 160*256){
            int r = idx/160, k = idx - r*160;
            float v = 0.0f;
            if (r < 256){ if (k < 32){ if (k < 16) v = g1Wih[r*16+k]; } else v = g1Whh[r*128 + (k-32)]; }
            else if (r < 384){ if (k < 16) v = g1Wih[r*16+k]; }
            else { if (k >= 32) v = g1Whh[(r-128)*128 + (k-32)]; }
            Wcat1[idx] = (f16)v;
        }
    } else if (b < 416){               // WcatA: INF=128, INFPAD=128, KTOT=256
        for (int idx = (b-160)*256+tid; idx < 512*256; idx += 256*256){
            int r = idx >> 8, k = idx & 255;
            float v = 0.0f;
            if (r < 256){ v = (k < 128) ? gaWih[r*128+k] : gaWhh[r*128 + (k-128)]; }
            else if (r < 384){ if (k < 128) v = gaWih[r*128+k]; }
            else { if (k >= 128) v = gaWhh[(r-128)*128 + (k-128)]; }
            WcatA[idx] = (f16)v;
        }
    } else if (b < 480){               // WT = giW^T (128x128)
        int idx = (b-416)*256+tid;
        int r = idx >> 7, c = idx & 127;
        WT[c*128 + r] = (f16)giW[idx];
    } else if (b < 672){               // fwT = fw^T (384x128 -> 128x384)
        int idx = (b-480)*256+tid;
        int r = idx >> 7, c = idx & 127;
        fwT[c*384 + r] = (f16)fw[idx];
    } else {                           // bucket
        if (tid < 16) cs[tid] = 0;
        __syncthreads();
        for (int s = tid; s < 2048; s += 256) atomicAdd(&cs[sec[s]], 1);
        __syncthreads();
        if (tid == 0){
            int acc = 0;
            for (int g=0; g<16; g++){ cnt[g]=cs[g]; base[g]=acc; wsc[g]=acc; acc+=cs[g]; }
        }
        __syncthreads();
        for (int s = tid; s < 2048; s += 256){
            int g = sec[s];
            int p = atomicAdd(&wsc[g], 1);
            memflat[p] = s;
        }
    }
}

// ---------------------------------------------------------------------------
// Short GRU+attn. M=32 seqs/block, 8 waves, T=5. Gate-partitioned MFMA,
// lagged unnormalized softmax (no max, no rescale), 1 barrier/step.
// __launch_bounds__(512,2): (512,4) caps VGPR at 64 -> 1.5 GB spill traffic
// (R5 post-mortem). 80 VGPR / 1 block/CU is the right point.
// ---------------------------------------------------------------------------
__global__ __launch_bounds__(512,2) void gru_short(
    const float* __restrict__ x, const f16* __restrict__ Wcat,
    const float* __restrict__ bih, const float* __restrict__ bhh,
    const float* __restrict__ aw, const float* __restrict__ ab,
    f16* __restrict__ out)
{
    __shared__ __align__(16) f16 xs[5][32][40];
    __shared__ __align__(16) f16 hs[2][32][136];
    __shared__ float scpart[2][8][32];
    const int tid = threadIdx.x, w = tid>>6, lane = tid&63;
    const int c = lane&15, quad = lane>>4;
    const int s0 = blockIdx.x*32;

    { f16x4 z4 = {0,0,0,0};
      f16x4* zx = (f16x4*)&xs[0][0][0];
      for (int i=tid; i<1600; i+=512) zx[i] = z4;
      f16x4* zh = (f16x4*)&hs[1][0][0];
      for (int i=tid; i<1088; i+=512) zh[i] = z4; }
    for (int i=tid; i<640; i+=512){
        int s = i/20, q = i - 20*s;
        float4 v = *(const float4*)&x[(size_t)(s0+s)*80 + q*4];
        int t = (q*4)>>4, f = (q*4)&15;
        f16x4 h4; h4[0]=(f16)v.x; h4[1]=(f16)v.y; h4[2]=(f16)v.z; h4[3]=(f16)v.w;
        *(f16x4*)&xs[t][s][f] = h4;
    }
    const int jrow = w*16 + c;
    f16x8 Ar[5], Az[5], Agi, Agh[4];
#pragma unroll
    for (int kb=0;kb<5;kb++){
        Ar[kb] = *(const f16x8*)&Wcat[(size_t)(jrow)*160 + kb*32 + quad*8];
        Az[kb] = *(const f16x8*)&Wcat[(size_t)(128+jrow)*160 + kb*32 + quad*8];
    }
    Agi = *(const f16x8*)&Wcat[(size_t)(256+jrow)*160 + quad*8];
#pragma unroll
    for (int i=0;i<4;i++)
        Agh[i] = *(const f16x8*)&Wcat[(size_t)(384+jrow)*160 + 32 + i*32 + quad*8];

    float brz_r[4], brz_z[4], b_in[4], b_hn[4], awr[4];
#pragma unroll
    for (int r=0;r<4;r++){
        int j = w*16 + quad*4 + r;
        brz_r[r] = bih[j] + bhh[j];
        brz_z[r] = bih[128+j] + bhh[128+j];
        b_in[r] = bih[256+j]; b_hn[r] = bhh[256+j];
        awr[r] = aw[j];
    }
    const float abv = ab[0];
    float hreg[2][4], aacc[2][4], l_[2] = {0.0f, 0.0f};
#pragma unroll
    for (int st=0; st<2; st++)
#pragma unroll
        for (int r=0;r<4;r++){ hreg[st][r]=0.0f; aacc[st][r]=0.0f; }
    __syncthreads();

#pragma unroll 1
    for (int t=0; t<5; ++t){
        const int rp = (t&1)^1, wp = t&1;
        f16x8 Bx[2], Bh[2][4];
#pragma unroll
        for (int st=0; st<2; st++){
            Bx[st] = *(const f16x8*)&xs[t][st*16+c][quad*8];
#pragma unroll
            for (int i=0;i<4;i++)
                Bh[st][i] = *(const f16x8*)&hs[rp][st*16+c][i*32+quad*8];
        }
        // lagged attention: apply step t-1's weight to h_{t-1} (still in hreg)
        if (t > 0){
#pragma unroll
            for (int st=0; st<2; st++){
                float sc = abv;
#pragma unroll
                for (int ww=0; ww<8; ww++) sc += scpart[rp][ww][st*16+c];
                float e = __expf(sc);
                l_[st] += e;
#pragma unroll
                for (int r=0;r<4;r++) aacc[st][r] += e*hreg[st][r];
            }
        }
        float sp[2];
#pragma unroll
        for (int st=0; st<2; st++){
            floatx4 ar = {0,0,0,0}, az = {0,0,0,0}, agi = {0,0,0,0}, agh = {0,0,0,0};
            ar = MFMA16(Ar[0], Bx[st], ar);
            az = MFMA16(Az[0], Bx[st], az);
            agi = MFMA16(Agi, Bx[st], agi);
#pragma unroll
            for (int i=0;i<4;i++){
                ar = MFMA16(Ar[1+i], Bh[st][i], ar);
                az = MFMA16(Az[1+i], Bh[st][i], az);
                agh = MFMA16(Agh[i], Bh[st][i], agh);
            }
            f16x4 h4;
            sp[st] = 0.0f;
#pragma unroll
            for (int r=0;r<4;r++){
                float rg = sigm_f(ar[r] + brz_r[r]);
                float zg = sigm_f(az[r] + brz_z[r]);
                float ng = tanh_f(agi[r] + b_in[r] + rg*(agh[r] + b_hn[r]));
                float hn = fmaf(zg, hreg[st][r] - ng, ng);
                hreg[st][r] = hn; h4[r] = (f16)hn;
                sp[st] += hn * awr[r];
            }
            *(f16x4*)&hs[wp][st*16 + c][w*16 + quad*4] = h4;
        }
#pragma unroll
        for (int st=0; st<2; st++){
            sp[st] += __shfl_xor(sp[st], 16);
            sp[st] += __shfl_xor(sp[st], 32);
        }
        if (lane < 16){ scpart[wp][w][lane] = sp[0]; scpart[wp][w][16+lane] = sp[1]; }
        __syncthreads();
    }
    // drain last step (t=4 wrote scpart[0], hreg holds h_4)
#pragma unroll
    for (int st=0; st<2; st++){
        float sc = abv;
#pragma unroll
        for (int ww=0; ww<8; ww++) sc += scpart[0][ww][st*16+c];
        float e = __expf(sc);
        l_[st] += e;
        float inv = rcpf(l_[st]);
        f16x4 h4;
#pragma unroll
        for (int r=0;r<4;r++) h4[r] = (f16)((aacc[st][r] + e*hreg[st][r])*inv);
        *(f16x4*)&hs[0][st*16 + c][w*16 + quad*4] = h4;
    }
    __syncthreads();
    { int s = tid>>4, p = tid&15;
      *(f16x8*)&out[(size_t)(s0+s)*128 + p*8] = *(const f16x8*)&hs[0][s][p*8]; }
}

// ---------------------------------------------------------------------------
// la GRU+attn. M=8 real seqs/block (16-tile padded), 256 blocks, T=32.
// Same lagged-softmax structure, 1 barrier/step. (512,2): see R5 spill note.
// ---------------------------------------------------------------------------
__global__ __launch_bounds__(512,2) void gru_la(
    const f16* __restrict__ xseq, const f16* __restrict__ Wcat,
    const float* __restrict__ bih, const float* __restrict__ bhh,
    const float* __restrict__ aw, const float* __restrict__ ab,
    f16* __restrict__ out)
{
    __shared__ __align__(16) f16 xs[2][16][136];
    __shared__ __align__(16) f16 hs[2][16][136];
    __shared__ float scpart[2][8][16];
    const int tid = threadIdx.x, w = tid>>6, lane = tid&63;
    const int c = lane&15, quad = lane>>4;
    const int s0 = blockIdx.x*8;

    { f16x4 z4 = {0,0,0,0};
      f16x4* za = (f16x4*)&xs[0][0][0];
      for (int i=tid; i<1088; i+=512) za[i] = z4;
      f16x4* zh = (f16x4*)&hs[0][0][0];
      for (int i=tid; i<1088; i+=512) zh[i] = z4; }
    __syncthreads();
    if (tid < 128){
        int s = tid>>4, p = tid&15;
        *(f16x8*)&xs[0][s][p*8] = *(const f16x8*)&xseq[((size_t)(s0+s)*32 + 0)*128 + p*8];
    }
    const int jrow = w*16 + c;
    f16x8 Ar[8], Az[8], Agi[4], Agh[4];
#pragma unroll
    for (int kb=0;kb<8;kb++){
        Ar[kb] = *(const f16x8*)&Wcat[(size_t)(jrow)*256 + kb*32 + quad*8];
        Az[kb] = *(const f16x8*)&Wcat[(size_t)(128+jrow)*256 + kb*32 + quad*8];
    }
#pragma unroll
    for (int i=0;i<4;i++){
        Agi[i] = *(const f16x8*)&Wcat[(size_t)(256+jrow)*256 + i*32 + quad*8];
        Agh[i] = *(const f16x8*)&Wcat[(size_t)(384+jrow)*256 + 128 + i*32 + quad*8];
    }
    float brz_r[4], brz_z[4], b_in[4], b_hn[4], awr[4];
#pragma unroll
    for (int r=0;r<4;r++){
        int j = w*16 + quad*4 + r;
        brz_r[r] = bih[j] + bhh[j];
        brz_z[r] = bih[128+j] + bhh[128+j];
        b_in[r] = bih[256+j]; b_hn[r] = bhh[256+j];
        awr[r] = aw[j];
    }
    const float abv = ab[0];
    float hreg[4] = {0,0,0,0}, aacc[4] = {0,0,0,0}, l_ = 0.0f;
    __syncthreads();

#pragma unroll 1
    for (int t=0; t<32; ++t){
        const int rp = (t&1)^1, wp = t&1, xp = t&1;
        f16x8 Bx[4], Bh[4];
#pragma unroll
        for (int i=0;i<4;i++){
            Bx[i] = *(const f16x8*)&xs[xp][c][i*32+quad*8];
            Bh[i] = *(const f16x8*)&hs[rp][c][i*32+quad*8];
        }
        f16x8 xstage;
        const bool do_stage = (t < 31) && (tid < 128);
        if (do_stage){
            int s = tid>>4, p = tid&15;
            xstage = *(const f16x8*)&xseq[((size_t)(s0+s)*32 + t+1)*128 + p*8];
        }
        if (t > 0){
            float sc = abv;
#pragma unroll
            for (int ww=0; ww<8; ww++) sc += scpart[rp][ww][c];
            float e = __expf(sc);
            l_ += e;
#pragma unroll
            for (int r=0;r<4;r++) aacc[r] += e*hreg[r];
        }
        floatx4 ar = {0,0,0,0}, az = {0,0,0,0}, agi = {0,0,0,0}, agh = {0,0,0,0};
#pragma unroll
        for (int i=0;i<4;i++){
            ar = MFMA16(Ar[i], Bx[i], ar);
            az = MFMA16(Az[i], Bx[i], az);
            agi = MFMA16(Agi[i], Bx[i], agi);
        }
#pragma unroll
        for (int i=0;i<4;i++){
            ar = MFMA16(Ar[4+i], Bh[i], ar);
            az = MFMA16(Az[4+i], Bh[i], az);
            agh = MFMA16(Agh[i], Bh[i], agh);
        }
        f16x4 h4;
        float sp = 0.0f;
#pragma unroll
        for (int r=0;r<4;r++){
            float rg = sigm_f(ar[r] + brz_r[r]);
            float zg = sigm_f(az[r] + brz_z[r]);
            float ng = tanh_f(agi[r] + b_in[r] + rg*(agh[r] + b_hn[r]));
            float hn = fmaf(zg, hreg[r] - ng, ng);
            hreg[r] = hn; h4[r] = (f16)hn;
            sp += hn * awr[r];
        }
        *(f16x4*)&hs[wp][c][w*16 + quad*4] = h4;
        if (do_stage){
            int s = tid>>4, p = tid&15;
            *(f16x8*)&xs[xp^1][s][p*8] = xstage;
        }
        sp += __shfl_xor(sp, 16);
        sp += __shfl_xor(sp, 32);
        if (lane < 16) scpart[wp][w][lane] = sp;
        __syncthreads();
    }
    // drain (t=31 wrote scpart[1])
    {
        float sc = abv;
#pragma unroll
        for (int ww=0; ww<8; ww++) sc += scpart[1][ww][c];
        float e = __expf(sc);
        l_ += e;
        float inv = rcpf(l_);
        f16x4 h4;
#pragma unroll
        for (int r=0;r<4;r++) h4[r] = (f16)((aacc[r] + e*hreg[r])*inv);
        *(f16x4*)&hs[1][c][w*16 + quad*4] = h4;
    }
    __syncthreads();
    if (tid < 128){
        int s = tid>>4, p = tid&15;
        *(f16x8*)&out[(size_t)(s0+s)*128 + p*8] = *(const f16x8*)&hs[1][s][p*8];
    }
}

// ---------------------------------------------------------------------------
// gat_prep: per 32 sorted rows — Wh=h@W (MFMA), sorted f16 Whs, ers, el[orig]
// ---------------------------------------------------------------------------
__global__ __launch_bounds__(256) void gat_prep(
    const f16* __restrict__ shrt16, const f16* __restrict__ WT,
    const float* __restrict__ gia, const int* __restrict__ memflat,
    f16* __restrict__ Whs, float* __restrict__ ers, float* __restrict__ el)
{
    __shared__ __align__(16) float tbuf[32][132];
    __shared__ int rows[32];
    const int tid = threadIdx.x, w = tid>>6, lane = tid&63;
    const int c = lane&15, quad = lane>>4;
    const int p0 = blockIdx.x*32;
    if (tid < 32) rows[tid] = memflat[p0 + tid];
    __syncthreads();
    f16x8 A[2][4];
#pragma unroll
    for (int mt=0;mt<2;mt++)
#pragma unroll
        for (int kb=0;kb<4;kb++)
            A[mt][kb] = *(const f16x8*)&shrt16[((size_t)rows[mt*16+c]*32 + 31)*128 + kb*32 + quad*8];
#pragma unroll
    for (int i=0;i<2;i++){
        int jb = w*2 + i;
        f16x8 B[4];
#pragma unroll
        for (int kb=0;kb<4;kb++)
            B[kb] = *(const f16x8*)&WT[(size_t)(jb*16+c)*128 + kb*32 + quad*8];
        floatx4 acc[2] = {{0,0,0,0},{0,0,0,0}};
#pragma unroll
        for (int kb=0;kb<4;kb++){
            acc[0] = MFMA16(A[0][kb], B[kb], acc[0]);
            acc[1] = MFMA16(A[1][kb], B[kb], acc[1]);
        }
#pragma unroll
        for (int mt=0;mt<2;mt++)
#pragma unroll
            for (int r=0;r<4;r++)
                tbuf[mt*16 + quad*4 + r][jb*16 + c] = acc[mt][r];
    }
    __syncthreads();
    // sorted f16 Wh
    for (int i=tid; i<1024; i+=256){
        int s = i>>5, p = i&31;
        float4 v = *(const float4*)&tbuf[s][p*4];
        f16x4 h4; h4[0]=(f16)v.x; h4[1]=(f16)v.y; h4[2]=(f16)v.z; h4[3]=(f16)v.w;
        *(f16x4*)&Whs[(size_t)(p0+s)*128 + p*4] = h4;
    }
    // el (orig-indexed), er (sorted)
    for (int k=0; k<8; k++){
        int row = w*8 + k;
        float w0 = tbuf[row][lane], w1 = tbuf[row][64+lane];
        float v1 = w0*gia[lane]     + w1*gia[64+lane];
        float v2 = w0*gia[128+lane] + w1*gia[192+lane];
#pragma unroll
        for (int off=32; off; off>>=1){ v1 += __shfl_down(v1,off); v2 += __shfl_down(v2,off); }
        if (lane==0){ el[rows[row]] = v1; ers[p0+row] = v2; }
    }
}

// ---------------------------------------------------------------------------
// GAT intra, member-list. One wave per row; streams sorted f16 Wh.
// ---------------------------------------------------------------------------
__global__ __launch_bounds__(256) void gat_intra_mem_kernel(
    const f16* __restrict__ Whs, const float* __restrict__ ers,
    const float* __restrict__ el, const int* __restrict__ sec,
    const int* __restrict__ cnt, const int* __restrict__ base,
    f16* __restrict__ outp, int S)
{
    int wave = threadIdx.x>>6, lane = threadIdx.x&63;
    int i = blockIdx.x*4 + wave;
    if (i>=S) return;
    int g = sec[i];
    int n = cnt[g], b = base[g];
    float eli = el[i];
    float m = -INFINITY;
    for (int jj=lane; jj<n; jj+=64){
        float v = eli + ers[b+jj]; v = v>0.f? v : LRELU_A*v;
        m = fmaxf(m, v);
    }
#pragma unroll
    for (int off=32; off; off>>=1) m = fmaxf(m, __shfl_xor(m, off));
    float l = 0.f, c0=0.f, c1=0.f;
#pragma unroll 4
    for (int jj=0; jj<n; jj++){
        float v = eli + ers[b+jj]; v = v>0.f? v : LRELU_A*v;
        float p = __expf(v-m);
        l += p;
        c0 += p*(float)Whs[(size_t)(b+jj)*128 + lane];
        c1 += p*(float)Whs[(size_t)(b+jj)*128 + 64 + lane];
    }
    float il = rcpf(l);
    c0 *= il; c1 *= il;
    outp[(size_t)i*128+lane]    = (f16)(c0>0.f? c0 : expm1f(c0));
    outp[(size_t)i*128+64+lane] = (f16)(c1>0.f? c1 : expm1f(c1));
}

// ---------------------------------------------------------------------------
// lg: T=1 GRU simplification via MFMA
// ---------------------------------------------------------------------------
__global__ __launch_bounds__(256) void lg_mfma(
    const f16* __restrict__ intra16, const float* __restrict__ Wih,
    const float* __restrict__ bih, const float* __restrict__ bhh,
    f16* __restrict__ lgout)
{
    __shared__ __align__(16) f16 tbuf[32][136];
    const int tid = threadIdx.x, w = tid>>6, lane = tid&63;
    const int c = lane&15, quad = lane>>4;
    const int s0 = blockIdx.x*32;
    f16x8 A[2][4];
#pragma unroll
    for (int mt=0;mt<2;mt++)
#pragma unroll
        for (int kb=0;kb<4;kb++)
            A[mt][kb] = *(const f16x8*)&intra16[(size_t)(s0+mt*16+c)*128 + kb*32 + quad*8];
#pragma unroll
    for (int i=0;i<2;i++){
        int jb = w*2 + i;
        int j = jb*16 + c;
        f16x8 Br[4], Bz[4], Bn[4];
#pragma unroll
        for (int kb=0;kb<4;kb++){
            Br[kb] = load_cvt8(&Wih[(size_t)(j)*128 + kb*32 + quad*8]);
            Bz[kb] = load_cvt8(&Wih[(size_t)(128+j)*128 + kb*32 + quad*8]);
            Bn[kb] = load_cvt8(&Wih[(size_t)(256+j)*128 + kb*32 + quad*8]);
        }
        float b_r = bih[j] + bhh[j];
        float b_z = bih[128+j] + bhh[128+j];
        float b_i = bih[256+j], b_h = bhh[256+j];
        floatx4 ar[2] = {{0,0,0,0},{0,0,0,0}};
        floatx4 az[2] = {{0,0,0,0},{0,0,0,0}};
        floatx4 an[2] = {{0,0,0,0},{0,0,0,0}};
#pragma unroll
        for (int kb=0;kb<4;kb++)
#pragma unroll
            for (int mt=0;mt<2;mt++){
                ar[mt] = MFMA16(A[mt][kb], Br[kb], ar[mt]);
                az[mt] = MFMA16(A[mt][kb], Bz[kb], az[mt]);
                an[mt] = MFMA16(A[mt][kb], Bn[kb], an[mt]);
            }
#pragma unroll
        for (int mt=0;mt<2;mt++)
#pragma unroll
            for (int r=0;r<4;r++){
                float rg = sigm_f(ar[mt][r] + b_r);
                float zg = sigm_f(az[mt][r] + b_z);
                float ng = tanh_f(an[mt][r] + b_i + rg*b_h);
                tbuf[mt*16 + quad*4 + r][j] = (f16)((1.0f - zg)*ng);
            }
    }
    __syncthreads();
    for (int i=tid; i<512; i+=256){
        int s = i>>4, p = i&15;
        *(f16x8*)&lgout[(size_t)(s0+s)*128 + p*8] = *(const f16x8*)&tbuf[s][p*8];
    }
}

// sector means via flat member lists
__global__ __launch_bounds__(128) void sector_mean_mem_kernel(
    const f16* __restrict__ lg, const int* __restrict__ memflat,
    const int* __restrict__ cnt, const int* __restrict__ base,
    float* __restrict__ secf)
{
    int g = blockIdx.x, j = threadIdx.x;
    int n = cnt[g];
    const int* ml = memflat + base[g];
    float sum=0.f;
    for (int k=0;k<n;k++) sum += (float)lg[(size_t)ml[k]*128 + j];
    secf[g*128+j] = sum * rcpf(fmaxf((float)n,1.0f));
}

__global__ __launch_bounds__(256) void gat_inter_kernel(
    const float* __restrict__ secf, const int* __restrict__ adj,
    const float* __restrict__ W, const float* __restrict__ a,
    float* __restrict__ outp)
{
    __shared__ __align__(16) float hs[16][132];
    __shared__ __align__(16) float Whs[16][132];
    __shared__ float el[16], er[16];
    __shared__ float att[16][16];
    const int tid=threadIdx.x;
    for (int idx=tid; idx<2048; idx+=256){ int s=idx>>7,j=idx&127; hs[s][j]=secf[idx]; }
    __syncthreads();
#pragma unroll 1
    for (int i=0;i<8;i++){
        int idx=i*256+tid; int o=idx&127, s=idx>>7;
        float a0=0.f,a1=0.f,a2=0.f,a3=0.f;
        for (int j=0;j<128;j+=4){
            a0 += hs[s][j]  *W[(j  )*128+o];
            a1 += hs[s][j+1]*W[(j+1)*128+o];
            a2 += hs[s][j+2]*W[(j+2)*128+o];
            a3 += hs[s][j+3]*W[(j+3)*128+o];
        }
        Whs[s][o]=(a0+a1)+(a2+a3);
    }
    __syncthreads();
    if (tid<32){
        int s=tid&15; int second = tid>>4;
        const float* av = a + (second?128:0);
        float acc=0.f; for(int o=0;o<128;o++) acc += Whs[s][o]*av[o];
        if (second) er[s]=acc; else el[s]=acc;
    }
    __syncthreads();
    if (tid<16){
        int i=tid; float m=NEGBIG; float e[16];
        for(int j=0;j<16;j++){
            float v = el[i]+er[j]; v = v>0.f? v : LRELU_A*v;
            e[j] = (adj[i*16+j]>0)? v : NEGBIG;
            m = fmaxf(m,e[j]);
        }
        float l=0.f;
        for(int j=0;j<16;j++){ float p=__expf(e[j]-m); att[i][j]=p; l+=p; }
        float il = rcpf(l);
        for(int j=0;j<16;j++) att[i][j] *= il;
    }
    __syncthreads();
#pragma unroll
    for (int i=0;i<8;i++){
        int idx=i*256+tid; int o=idx&127, s=idx>>7;
        float acc=0.f;
#pragma unroll
        for(int j=0;j<16;j++) acc += att[s][j]*Whs[j][o];
        outp[s*128+o] = acc>0.f? acc : expm1f(acc);
    }
}

// ---------------------------------------------------------------------------
// fused = [lg|la|sec_ps] @ fw + fb, then both heads in-kernel
// ---------------------------------------------------------------------------
__global__ __launch_bounds__(256) void fused_mfma(
    const f16* __restrict__ lg16, const f16* __restrict__ la16,
    const float* __restrict__ seco, const int* __restrict__ sec,
    const f16* __restrict__ fwT,
    const float* __restrict__ fb, const float* __restrict__ rw,
    const float* __restrict__ rb, const float* __restrict__ mw,
    const float* __restrict__ mb, float* __restrict__ outp)
{
    __shared__ float rpart[4][32], mpart[4][32];
    const int tid = threadIdx.x, w = tid>>6, lane = tid&63;
    const int c = lane&15, quad = lane>>4;
    const int s0 = blockIdx.x*32;
    f16x8 A[2][12];
#pragma unroll
    for (int mt=0;mt<2;mt++){
        int row = s0 + mt*16 + c;
        int g = sec[row];
#pragma unroll
        for (int kb=0;kb<4;kb++){
            A[mt][kb]   = *(const f16x8*)&lg16[(size_t)row*128 + kb*32 + quad*8];
            A[mt][4+kb] = *(const f16x8*)&la16[(size_t)row*128 + kb*32 + quad*8];
            A[mt][8+kb] = load_cvt8(&seco[(size_t)g*128 + kb*32 + quad*8]);
        }
    }
    float rsum[2][4] = {{0,0,0,0},{0,0,0,0}};
    float msum[2][4] = {{0,0,0,0},{0,0,0,0}};
#pragma unroll
    for (int i=0;i<2;i++){
        int jb = w*2 + i;
        int col = jb*16 + c;
        f16x8 B[12];
#pragma unroll
        for (int kb=0;kb<12;kb++)
            B[kb] = *(const f16x8*)&fwT[(size_t)col*384 + kb*32 + quad*8];
        floatx4 acc[2] = {{0,0,0,0},{0,0,0,0}};
#pragma unroll
        for (int kb=0;kb<12;kb++){
            acc[0] = MFMA16(A[0][kb], B[kb], acc[0]);
            acc[1] = MFMA16(A[1][kb], B[kb], acc[1]);
        }
        float fbv = fb[col], rwv = rw[col], mwv = mw[col];
#pragma unroll
        for (int mt=0;mt<2;mt++)
#pragma unroll
            for (int r=0;r<4;r++){
                float fu = acc[mt][r] + fbv;
                rsum[mt][r] += fu*rwv;
                msum[mt][r] += fu*mwv;
            }
    }
#pragma unroll
    for (int mt=0;mt<2;mt++)
#pragma unroll
        for (int r=0;r<4;r++){
#pragma unroll
            for (int off=1; off<16; off<<=1){
                rsum[mt][r] += __shfl_xor(rsum[mt][r], off);
                msum[mt][r] += __shfl_xor(msum[mt][r], off);
            }
            if (c==0){
                rpart[w][mt*16 + quad*4 + r] = rsum[mt][r];
                mpart[w][mt*16 + quad*4 + r] = msum[mt][r];
            }
        }
    __syncthreads();
    if (tid < 32){
        int s = tid;
        float rs = rb[0], ms = mb[0];
#pragma unroll
        for (int ww=0; ww<4; ww++){ rs += rpart[ww][s]; ms += mpart[ww][s]; }
        outp[s0+s] = rs;
        outp[2048 + s0 + s] = sigm(ms);
    }
}

extern "C" void kernel_launch(void* const* d_in, const int* in_sizes, int n_in,
                              void* d_out, int out_size, void* d_ws, size_t ws_size,
                              hipStream_t stream) {
    const float* sf    = (const float*)d_in[0];
    const int*   sec   = (const int*)  d_in[1];
    const int*   adj   = (const int*)  d_in[2];
    const float* g1Wih = (const float*)d_in[3];
    const float* g1Whh = (const float*)d_in[4];
    const float* g1bih = (const float*)d_in[5];
    const float* g1bhh = (const float*)d_in[6];
    const float* a1w   = (const float*)d_in[7];
    const float* a1b   = (const float*)d_in[8];
    const float* giW   = (const float*)d_in[9];
    const float* gia   = (const float*)d_in[10];
    const float* ggWih = (const float*)d_in[11];
    const float* ggbih = (const float*)d_in[13];
    const float* ggbhh = (const float*)d_in[14];
    const float* gaWih = (const float*)d_in[17];
    const float* gaWhh = (const float*)d_in[18];
    const float* gabih = (const float*)d_in[19];
    const float* gabhh = (const float*)d_in[20];
    const float* aaw   = (const float*)d_in[21];
    const float* aab   = (const float*)d_in[22];
    const float* geW   = (const float*)d_in[23];
    const float* gea   = (const float*)d_in[24];
    const float* fw    = (const float*)d_in[25];
    const float* fb    = (const float*)d_in[26];
    const float* rw    = (const float*)d_in[27];
    const float* rb    = (const float*)d_in[28];
    const float* mw    = (const float*)d_in[29];
    const float* mb    = (const float*)d_in[30];

    char* p = (char*)d_ws;
    f16*   shrt16 = (f16*)p;   p += (size_t)65536*128*2;
    f16*   intra16= (f16*)p;   p += (size_t)262144*2;
    f16*   lg16   = (f16*)p;   p += (size_t)262144*2;
    f16*   la16   = (f16*)p;   p += (size_t)262144*2;
    f16*   Whs    = (f16*)p;   p += (size_t)262144*2;
    f16*   Wcat1  = (f16*)p;   p += (size_t)512*160*2;
    f16*   WcatA  = (f16*)p;   p += (size_t)512*256*2;
    f16*   WT     = (f16*)p;   p += (size_t)16384*2;
    f16*   fwT    = (f16*)p;   p += (size_t)49152*2;
    float* el     = (float*)p; p += 2048*4;
    float* ers    = (float*)p; p += 2048*4;
    float* secf   = (float*)p; p += 2048*4;
    float* seco   = (float*)p; p += 2048*4;
    int*   memflat= (int*)p;   p += 2048*4;
    int*   cnt    = (int*)p;   p += 16*4;
    int*   basep  = (int*)p;   p += 16*4;

    // 0. all weight prep + bucketing in one launch
    prep_kernel<<<673,256,0,stream>>>(g1Wih, g1Whh, gaWih, gaWhh, giW, fw, sec,
                                      Wcat1, WcatA, WT, fwT, memflat, cnt, basep);
    // 1. short GRU+attn (65536 windows, T=5)
    gru_short<<<2048,512,0,stream>>>(sf, Wcat1, g1bih, g1bhh, a1w, a1b, shrt16);
    // 2. intra-sector GAT (prep fused: Wh + el/er + sorted gather)
    gat_prep<<<64,256,0,stream>>>(shrt16, WT, gia, memflat, Whs, ers, el);
    gat_intra_mem_kernel<<<512,256,0,stream>>>(Whs, ers, el, sec, cnt, basep, intra16, 2048);
    // 3. lg (T=1 simplification)
    lg_mfma<<<64,256,0,stream>>>(intra16, ggWih, ggbih, ggbhh, lg16);
    // 4. la GRU+attn (2048 seqs, T=32, M=8 -> all CUs)
    gru_la<<<256,512,0,stream>>>(shrt16, WcatA, gabih, gabhh, aaw, aab, la16);
    // 5. sector means
    sector_mean_mem_kernel<<<16,128,0,stream>>>(lg16, memflat, cnt, basep, secf);
    // 6. inter-sector GAT
    gat_inter_kernel<<<1,256,0,stream>>>(secf, adj, geW, gea, seco);
    // 7. fusion + heads
    fused_mfma<<<64,256,0,stream>>>(lg16, la16, seco, sec, fwT, fb, rw, rb, mw, mb, (float*)d_out);
}